// Round 5
// baseline (2750.956 us; speedup 1.0000x reference)
//
#include <hip/hip_runtime.h>
#include <math.h>

#define B_ROWS 32768
#define D_DIM  512
#define K_EMB  8192

#define BMT 128
#define BNT 128
#define RSPLIT 16
#define KRANGE_R (K_EMB / RSPLIT)   // 512
#define EPS 0.10f

typedef __attribute__((ext_vector_type(4))) float f32x4;
typedef __attribute__((ext_vector_type(8))) short bf16x8;

#define GLL16(gp, lp)                                                          \
  __builtin_amdgcn_global_load_lds(                                            \
      (const __attribute__((address_space(1))) void*)(gp),                     \
      (__attribute__((address_space(3))) void*)(lp), 16, 0, 0)

// ---------------------------------------------------------------------------
// fp32 -> bf16 hi + residual lo (RNE), fused with row squared-norm.
// ---------------------------------------------------------------------------
__device__ __forceinline__ unsigned bf_rne(float x) {
  unsigned u = __float_as_uint(x);
  return (u + 0x7fffu + ((u >> 16) & 1u)) >> 16;
}

__global__ __launch_bounds__(256) void prep_kernel(
    const float* __restrict__ X, short* __restrict__ hi,
    short* __restrict__ lo, float* __restrict__ sq, int nrows) {
  const int wave = threadIdx.x >> 6;
  const int lane = threadIdx.x & 63;
  const int row = blockIdx.x * 4 + wave;
  if (row >= nrows) return;
  const float* xr = X + (size_t)row * D_DIM;
  float4 x0 = ((const float4*)xr)[lane * 2];
  float4 x1 = ((const float4*)xr)[lane * 2 + 1];
  float xs[8] = {x0.x, x0.y, x0.z, x0.w, x1.x, x1.y, x1.z, x1.w};
  union { short s[8]; int4 v; } H, L;
  float ssum = 0.f;
  #pragma unroll
  for (int j = 0; j < 8; ++j) {
    unsigned rh = bf_rne(xs[j]);
    H.s[j] = (short)rh;
    float h = __uint_as_float(rh << 16);
    L.s[j] = (short)bf_rne(xs[j] - h);
    ssum += xs[j] * xs[j];
  }
  *(int4*)(hi + (size_t)row * D_DIM + lane * 8) = H.v;
  *(int4*)(lo + (size_t)row * D_DIM + lane * 8) = L.v;
  #pragma unroll
  for (int o = 32; o > 0; o >>= 1) ssum += __shfl_xor(ssum, o, 64);
  if (lane == 0) sq[row] = ssum;
}

// ---------------------------------------------------------------------------
// Stage 1: persistent-z hi*hi top-2 argmin, barrier-free k-loop.
// V5: R1/R4 post-mortem showed a ~2.4Kcy/chunk serial wall INVARIANT to
// occupancy (2->4 waves/SIMD) and per-chunk width (16->8 MFMA) => per-wave
// B-load dependency chain at depth-1 prefetch, with latency inflated by
// same-line L2 contention (all blocks sweep W in lockstep; ~64 blocks/XCD
// hit the same 64B lines simultaneously). Two fixes:
//  (a) explicit depth-3-in-flight B register pipeline (4 rotating slots,
//      static indices via full unroll) -- 6 loads in flight per wave;
//  (b) staggered k-sweep: block starts at k-tile ((bid>>3)&7)*4, so per-XCD
//      blocks spread over 8 sweep positions (8x less same-line contention,
//      2 MB/XCD L2 working set). Sweep no longer ascending => tie-break
//      compare restored in scoring (argmin = lowest index on ties).
// ---------------------------------------------------------------------------
__global__ __launch_bounds__(512, 4) void stage1_kernel(
    const short* __restrict__ zhi, const short* __restrict__ whi,
    const float* __restrict__ wsq, float* __restrict__ cv1,
    int* __restrict__ ci1, float* __restrict__ cv2) {
  __shared__ short Zt[32768];   // 64 KB: [dc 0..63][row 0..63][8 bf16]
  float* rv1 = (float*)Zt;             // post-loop overlay: [64][8] f32 (2 KB)
  int*   ri1 = (int*)(Zt + 1024);      // +2 KB
  float* rv2 = (float*)(Zt + 2048);    // +4 KB

  const int tid = threadIdx.x;
  const int lane = tid & 63;
  const int wave = tid >> 6;     // 0..7 = code slice (wn)
  const int l15 = lane & 15, l4 = lane >> 4;
  const int row0 = blockIdx.x * 64;
  const int off = ((blockIdx.x >> 3) & 7) * 4;   // sweep-start k-tile (0..28)

  // one-time z-tile load (slot = dc*64 + row; LDS dest = slot*16 B)
  #pragma unroll
  for (int j = 0; j < 8; ++j) {
    const int slot = j * 512 + tid;
    const int r = slot & 63, dc = slot >> 6;
    GLL16(zhi + (size_t)(row0 + r) * D_DIM + dc * 8, Zt + (size_t)slot * 8);
  }

  // per-lane B base pointers: code = wave*32 + cb*16 + l15, d-subchunk = l4*8
  const short* pb[2];
  #pragma unroll
  for (int cb = 0; cb < 2; ++cb)
    pb[cb] = whi + (size_t)(wave * 32 + cb * 16 + l15) * D_DIM + l4 * 8;

  // logical chunk lg (sweep order) -> byte-element offset from pb.
  // physical k-tile = (lg/16 + off) & 31 (wrap keeps every address in-bounds,
  // incl. the tail's lg+3 dummy prefetches).
  auto b_off = [&](int lg) -> size_t {
    const int pt = ((lg >> 4) + off) & 31;
    return (size_t)(pt * 256) * D_DIM + (size_t)((lg & 15) * 32);
  };

  float v1[16], v2[16];
  int   i1[16];
  #pragma unroll
  for (int s = 0; s < 16; ++s) { v1[s] = INFINITY; v2[s] = INFINITY; i1[s] = 0x7fffffff; }

  // B register pipeline: 4 slots, loads issued 3 logical chunks ahead.
  bf16x8 bp[4][2];
  #pragma unroll
  for (int p = 0; p < 3; ++p) {
    const size_t o0 = b_off(p);
    #pragma unroll
    for (int cb = 0; cb < 2; ++cb) bp[p][cb] = *(const bf16x8*)(pb[cb] + o0);
  }

  __syncthreads();  // z-tile DMA complete & visible; the ONLY pre-loop barrier

  for (int t = 0; t < 32; ++t) {            // logical k-tile in sweep order
    const int ktc = (((t + off) & 31) << 8);  // physical code base of tile
    f32x4 acc[4][2];
    #pragma unroll
    for (int rb = 0; rb < 4; ++rb)
      #pragma unroll
      for (int cb = 0; cb < 2; ++cb) acc[rb][cb] = (f32x4)0.f;

    #pragma unroll
    for (int dc = 0; dc < 16; ++dc) {
      const int lg = t * 16 + dc;
      // A fragments for current chunk (LDS; lgkm hidden by 4-wave interleave)
      bf16x8 a[4];
      #pragma unroll
      for (int rb = 0; rb < 4; ++rb)
        a[rb] = *(const bf16x8*)&Zt[((dc * 4 + l4) * 64 + rb * 16 + l15) * 8];
      // issue B loads 3 chunks ahead into slot (dc+3)&3 (static index)
      {
        const size_t o3 = b_off(lg + 3);
        #pragma unroll
        for (int cb = 0; cb < 2; ++cb)
          bp[(dc + 3) & 3][cb] = *(const bf16x8*)(pb[cb] + o3);
      }
      // MFMA consumes slot dc&3 (loaded 3 iterations ago)
      #pragma unroll
      for (int rb = 0; rb < 4; ++rb)
        #pragma unroll
        for (int cb = 0; cb < 2; ++cb)
          acc[rb][cb] = __builtin_amdgcn_mfma_f32_16x16x32_bf16(
              a[rb], bp[dc & 3][cb], acc[rb][cb], 0, 0, 0);
    }

    // score 256-code tile; C/D layout: col=lane&15, row=(lane>>4)*4+reg.
    // staggered sweep is NOT ascending in code index -> explicit tie-break.
    #pragma unroll
    for (int cb = 0; cb < 2; ++cb) {
      const int col = ktc + wave * 32 + cb * 16 + l15;
      const float wv = wsq[col];
      #pragma unroll
      for (int rb = 0; rb < 4; ++rb) {
        f32x4 a = acc[rb][cb];
        #pragma unroll
        for (int rg = 0; rg < 4; ++rg) {
          const float dist = wv - 2.0f * a[rg];
          const int s = rb * 4 + rg;
          if (dist < v1[s] || (dist == v1[s] && col < i1[s])) {
            v2[s] = v1[s]; v1[s] = dist; i1[s] = col;
          } else {
            v2[s] = fminf(v2[s], dist);
          }
        }
      }
    }
  }

  // in-register top-2 merge across the 16 col-classes (lanes l4*16 .. +15
  // all hold the same physical rows; xor masks 1,2,4,8 stay in-group).
  __syncthreads();  // compute done; Zt dead -> overlay
  #pragma unroll
  for (int s = 0; s < 16; ++s) {
    float a1 = v1[s], a2 = v2[s];
    int ai = i1[s];
    #pragma unroll
    for (int m = 1; m < 16; m <<= 1) {
      const float b1 = __shfl_xor(a1, m, 64);
      const float b2 = __shfl_xor(a2, m, 64);
      const int   bi = __shfl_xor(ai, m, 64);
      if (b1 < a1 || (b1 == a1 && bi < ai)) {
        a2 = fminf(a1, b2); a1 = b1; ai = bi;
      } else {
        a2 = fminf(a2, b1);
      }
    }
    if (l15 == 0) {
      const int r = (s >> 2) * 16 + l4 * 4 + (s & 3);
      rv1[r * 8 + wave] = a1;
      ri1[r * 8 + wave] = ai;
      rv2[r * 8 + wave] = a2;
    }
  }
  __syncthreads();

  if (tid < 64) {
    float V1 = INFINITY, V2 = INFINITY;
    int I1 = 0x7fffffff;
    #pragma unroll
    for (int w = 0; w < 8; ++w) {
      const float a1 = rv1[tid * 8 + w];
      const int ai = ri1[tid * 8 + w];
      const float a2 = rv2[tid * 8 + w];
      if (a1 < V1 || (a1 == V1 && ai < I1)) {
        V2 = fminf(V1, a2); V1 = a1; I1 = ai;
      } else {
        V2 = fminf(V2, a1);
      }
    }
    cv1[row0 + tid] = V1; ci1[row0 + tid] = I1; cv2[row0 + tid] = V2;
  }
}

// ---------------------------------------------------------------------------
// Commit unambiguous rows; compact ambiguous rows into refine list.
// ---------------------------------------------------------------------------
__global__ __launch_bounds__(256) void merge_flag_kernel(
    const float* __restrict__ cv1, const int* __restrict__ ci1,
    const float* __restrict__ cv2, int* __restrict__ idx,
    float* __restrict__ out_idx_f, int* __restrict__ hist,
    unsigned long long* __restrict__ packed, int* __restrict__ cnt,
    int* __restrict__ list) {
  const int row = blockIdx.x * 256 + threadIdx.x;
  const float V1 = cv1[row];
  const int I1 = ci1[row];
  const float V2 = cv2[row];
  if (V2 - V1 >= EPS) {
    idx[row] = I1;
    out_idx_f[row] = (float)I1;
    atomicAdd(&hist[I1], 1);
  } else {
    packed[row] = 0xffffffffffffffffULL;
    const int p = atomicAdd(cnt, 1);
    list[p] = row;
  }
}

// ---------------------------------------------------------------------------
// Refine: exact 3-pass distance argmin over ALL codes for flagged rows.
// Split-K=16, merged via packed atomicMin (value-then-lowest-idx order).
// ---------------------------------------------------------------------------
__global__ __launch_bounds__(256, 2) void refine_kernel(
    const short* __restrict__ zhi, const short* __restrict__ zlo,
    const short* __restrict__ whi, const short* __restrict__ wlo,
    const float* __restrict__ zz, const float* __restrict__ wsq,
    const int* __restrict__ cnt, const int* __restrict__ list,
    unsigned long long* __restrict__ packed) {
  __shared__ char smem[32768];
  short* Ah = (short*)smem;
  short* Al = (short*)(smem + 8192);
  short* Bh = (short*)(smem + 16384);
  short* Bl = (short*)(smem + 24576);
  float* rv = (float*)smem;
  int*   ri = (int*)(smem + 16384);

  const int n = *cnt;
  const int bx = blockIdx.x;
  const int rt = bx >> 4;
  const int ks = bx & 15;
  if (rt * BMT >= n) return;
  const int k0 = ks * KRANGE_R;

  const int tid = threadIdx.x;
  const int lane = tid & 63;
  const int wave = tid >> 6;
  const int wm = wave >> 1, wn = wave & 1;
  const int l15 = lane & 15, l4 = lane >> 4;

  const int r0s = tid & 127;
  const int kc0 = tid >> 7;
  const int kc1 = kc0 + 2;
  const int rowg = list[min(rt * BMT + r0s, n - 1)];

  float zzr[16];
  #pragma unroll
  for (int rb = 0; rb < 4; ++rb)
    #pragma unroll
    for (int rg = 0; rg < 4; ++rg) {
      const int m = wm * 64 + rb * 16 + l4 * 4 + rg;
      zzr[rb * 4 + rg] = zz[list[min(rt * BMT + m, n - 1)]];
    }

  float best[16];
  int   bidx[16];
  #pragma unroll
  for (int s = 0; s < 16; ++s) { best[s] = INFINITY; bidx[s] = 0x7fffffff; }

  for (int kt = 0; kt < KRANGE_R; kt += BNT) {
    f32x4 acc[4][4];
    #pragma unroll
    for (int rb = 0; rb < 4; ++rb)
      #pragma unroll
      for (int cb = 0; cb < 4; ++cb) acc[rb][cb] = (f32x4)0.f;

    for (int d0 = 0; d0 < D_DIM; d0 += 32) {
      const size_t ga0 = (size_t)rowg * D_DIM + d0 + kc0 * 8;
      const size_t ga1 = (size_t)rowg * D_DIM + d0 + kc1 * 8;
      const size_t gb0 = (size_t)(k0 + kt + r0s) * D_DIM + d0 + kc0 * 8;
      const size_t gb1 = (size_t)(k0 + kt + r0s) * D_DIM + d0 + kc1 * 8;
      GLL16(zhi + ga0, Ah + (size_t)tid * 8);
      GLL16(zhi + ga1, Ah + (size_t)(tid + 256) * 8);
      GLL16(zlo + ga0, Al + (size_t)tid * 8);
      GLL16(zlo + ga1, Al + (size_t)(tid + 256) * 8);
      GLL16(whi + gb0, Bh + (size_t)tid * 8);
      GLL16(whi + gb1, Bh + (size_t)(tid + 256) * 8);
      GLL16(wlo + gb0, Bl + (size_t)tid * 8);
      GLL16(wlo + gb1, Bl + (size_t)(tid + 256) * 8);
      __syncthreads();

      bf16x8 ah[4], al[4], bh[4], bl[4];
      #pragma unroll
      for (int rb = 0; rb < 4; ++rb) {
        const int m = wm * 64 + rb * 16 + l15;
        ah[rb] = *(const bf16x8*)&Ah[(l4 * 128 + m) * 8];
        al[rb] = *(const bf16x8*)&Al[(l4 * 128 + m) * 8];
      }
      #pragma unroll
      for (int cb = 0; cb < 4; ++cb) {
        const int nn = wn * 64 + cb * 16 + l15;
        bh[cb] = *(const bf16x8*)&Bh[(l4 * 128 + nn) * 8];
        bl[cb] = *(const bf16x8*)&Bl[(l4 * 128 + nn) * 8];
      }
      #pragma unroll
      for (int rb = 0; rb < 4; ++rb)
        #pragma unroll
        for (int cb = 0; cb < 4; ++cb) {
          acc[rb][cb] = __builtin_amdgcn_mfma_f32_16x16x32_bf16(
              ah[rb], bh[cb], acc[rb][cb], 0, 0, 0);
          acc[rb][cb] = __builtin_amdgcn_mfma_f32_16x16x32_bf16(
              ah[rb], bl[cb], acc[rb][cb], 0, 0, 0);
          acc[rb][cb] = __builtin_amdgcn_mfma_f32_16x16x32_bf16(
              al[rb], bh[cb], acc[rb][cb], 0, 0, 0);
        }
      __syncthreads();
    }

    #pragma unroll
    for (int cb = 0; cb < 4; ++cb) {
      const int col = k0 + kt + wn * 64 + cb * 16 + l15;
      const float wv = wsq[col];
      #pragma unroll
      for (int rb = 0; rb < 4; ++rb) {
        f32x4 a = acc[rb][cb];
        #pragma unroll
        for (int rg = 0; rg < 4; ++rg) {
          const float dist = (zzr[rb * 4 + rg] + wv) - 2.0f * a[rg];
          const int s = rb * 4 + rg;
          if (dist < best[s]) { best[s] = dist; bidx[s] = col; }
        }
      }
    }
  }

  #pragma unroll
  for (int rb = 0; rb < 4; ++rb)
    #pragma unroll
    for (int rg = 0; rg < 4; ++rg) {
      const int s = rb * 4 + rg;
      const int R = wm * 64 + rb * 16 + l4 * 4 + rg;
      rv[R * 32 + wn * 16 + l15] = best[s];
      ri[R * 32 + wn * 16 + l15] = bidx[s];
    }
  __syncthreads();

  if (tid < BMT && rt * BMT + tid < n) {
    float bv = INFINITY;
    int bi = 0x7fffffff;
    #pragma unroll
    for (int t = 0; t < 32; ++t) {
      const float v = rv[tid * 32 + t];
      const int ix = ri[tid * 32 + t];
      if (v < bv || (v == bv && ix < bi)) { bv = v; bi = ix; }
    }
    const int row = list[rt * BMT + tid];
    const unsigned long long pk =
        ((unsigned long long)__float_as_uint(bv) << 32) | (unsigned)bi;
    atomicMin(&packed[row], pk);
  }
}

// ---------------------------------------------------------------------------
__global__ __launch_bounds__(256) void final_merge_kernel(
    const int* __restrict__ cnt, const int* __restrict__ list,
    const unsigned long long* __restrict__ packed, int* __restrict__ idx,
    float* __restrict__ out_idx_f, int* __restrict__ hist) {
  const int t = blockIdx.x * 256 + threadIdx.x;
  if (t >= *cnt) return;
  const int row = list[t];
  const int bi = (int)(packed[row] & 0xffffffffULL);
  idx[row] = bi;
  out_idx_f[row] = (float)bi;
  atomicAdd(&hist[bi], 1);
}

// ---------------------------------------------------------------------------
// Gather + straight-through + per-block MSE partial (no global atomics).
// ---------------------------------------------------------------------------
__global__ __launch_bounds__(256) void gather_kernel(
    const float* __restrict__ z, const float* __restrict__ W,
    const int* __restrict__ idx, float* __restrict__ out,
    double* __restrict__ mse_part) {
  __shared__ float wsum[4];
  const int wave = threadIdx.x >> 6;
  const int lane = threadIdx.x & 63;
  const int row = blockIdx.x * 4 + wave;
  const int k = idx[row];
  const float* zr = z + (size_t)row * D_DIM;
  const float* wr = W + (size_t)k * D_DIM;
  float* outr = out + (size_t)row * D_DIM;
  float s = 0.f;
  #pragma unroll
  for (int h = 0; h < 2; ++h) {
    const int c = h * 256 + lane * 4;
    float4 zv = *(const float4*)(zr + c);
    float4 qv = *(const float4*)(wr + c);
    float4 st;
    st.x = zv.x + (qv.x - zv.x);
    st.y = zv.y + (qv.y - zv.y);
    st.z = zv.z + (qv.z - zv.z);
    st.w = zv.w + (qv.w - zv.w);
    float dx = zv.x - qv.x, dy = zv.y - qv.y, dz = zv.z - qv.z, dw = zv.w - qv.w;
    s += dx * dx + dy * dy + dz * dz + dw * dw;
    *(float4*)(outr + c) = st;
  }
  #pragma unroll
  for (int o = 32; o > 0; o >>= 1) s += __shfl_xor(s, o, 64);
  if (lane == 0) wsum[wave] = s;
  __syncthreads();
  if (threadIdx.x == 0)
    mse_part[blockIdx.x] =
        (double)wsum[0] + (double)wsum[1] + (double)wsum[2] + (double)wsum[3];
}

// ---------------------------------------------------------------------------
// Loss: entropy over histogram + MSE partial-sum reduction (8192 partials
// == K_EMB, so both fold into the same strided loop).
// ---------------------------------------------------------------------------
__global__ __launch_bounds__(256) void loss_kernel(
    const int* __restrict__ hist, const double* __restrict__ mse_part,
    float* __restrict__ out_loss) {
  __shared__ float ls[4];
  __shared__ double ld[4];
  const int tid = threadIdx.x;
  float e = 0.f;
  double ms = 0.0;
  for (int b = tid; b < K_EMB; b += 256) {
    float p = (float)hist[b] * (1.0f / 32768.0f);
    e += p * logf(p + 1e-10f);
    ms += mse_part[b];
  }
  #pragma unroll
  for (int o = 32; o > 0; o >>= 1) {
    e += __shfl_xor(e, o, 64);
    ms += __shfl_xor(ms, o, 64);
  }
  if ((tid & 63) == 0) { ls[tid >> 6] = e; ld[tid >> 6] = ms; }
  __syncthreads();
  if (tid == 0) {
    float entropy = -(ls[0] + ls[1] + ls[2] + ls[3]);
    float mse = (float)((ld[0] + ld[1] + ld[2] + ld[3]) / 16777216.0);
    float entropy_loss = 1.0f - entropy / logf(8192.0f);
    out_loss[0] = mse + 0.25f * mse + 0.1f * entropy_loss;
  }
}

// ---------------------------------------------------------------------------
extern "C" void kernel_launch(void* const* d_in, const int* in_sizes, int n_in,
                              void* d_out, int out_size, void* d_ws, size_t ws_size,
                              hipStream_t stream) {
  const float* z = (const float*)d_in[0];  // [32768,512]
  const float* W = (const float*)d_in[1];  // [8192,512]
  float* out = (float*)d_out;              // [B*D] st | [1] loss | [B] indices

  char* ws = (char*)d_ws;
  int*    cnt     = (int*)(ws + 8);                        // @8
  int*    hist    = (int*)(ws + 4096);                     // 32 KB
  unsigned long long* packed = (unsigned long long*)(ws + 65536);  // 256 KB
  float*  zz   = (float*)(ws + 327680);                    // 128 KB
  float*  wsq  = (float*)(ws + 458752);                    // 32 KB
  int*    idx  = (int*)(ws + 491520);                      // 128 KB
  int*    list = (int*)(ws + 622592);                      // 128 KB
  float*  cv1  = (float*)(ws + 786432);                    // [B_ROWS]
  int*    ci1  = (int*)(ws + 1310720);                     // [B_ROWS]
  float*  cv2  = (float*)(ws + 1835008);                   // [B_ROWS]
  double* mse_part = (double*)(ws + 2097152);              // 64 KB [8192]
  short*  zhi  = (short*)(ws + 4194304);                   // 32 MB
  short*  zlo  = (short*)(ws + 37748736);                  // 32 MB
  short*  whi  = (short*)(ws + 71303168);                  // 8 MB
  short*  wlo  = (short*)(ws + 79691776);                  // 8 MB (ends 84 MB)

  hipMemsetAsync(d_ws, 0, 36864, stream);  // cnt + hist

  prep_kernel<<<B_ROWS / 4, 256, 0, stream>>>(z, zhi, zlo, zz, B_ROWS);
  prep_kernel<<<K_EMB / 4, 256, 0, stream>>>(W, whi, wlo, wsq, K_EMB);

  stage1_kernel<<<B_ROWS / 64, 512, 0, stream>>>(zhi, whi, wsq, cv1, ci1, cv2);

  merge_flag_kernel<<<B_ROWS / 256, 256, 0, stream>>>(
      cv1, ci1, cv2, idx, out + (size_t)B_ROWS * D_DIM + 1, hist,
      packed, cnt, list);

  refine_kernel<<<(B_ROWS / BMT) * RSPLIT, 256, 0, stream>>>(
      zhi, zlo, whi, wlo, zz, wsq, cnt, list, packed);

  final_merge_kernel<<<B_ROWS / 256, 256, 0, stream>>>(
      cnt, list, packed, idx, out + (size_t)B_ROWS * D_DIM + 1, hist);

  gather_kernel<<<B_ROWS / 4, 256, 0, stream>>>(z, W, idx, out, mse_part);

  loss_kernel<<<1, 256, 0, stream>>>(hist, mse_part,
                                     out + (size_t)B_ROWS * D_DIM);
}

// Round 6
// 1856.394 us; speedup vs baseline: 1.4819x; 1.4819x over previous
//
#include <hip/hip_runtime.h>
#include <math.h>

#define B_ROWS 32768
#define D_DIM  512
#define K_EMB  8192

#define BMT 128
#define BNT 128
#define RSPLIT 16
#define KRANGE_R (K_EMB / RSPLIT)   // 512
#define EPS 0.10f

typedef __attribute__((ext_vector_type(4))) float f32x4;
typedef __attribute__((ext_vector_type(8))) short bf16x8;

#define GLL16(gp, lp)                                                          \
  __builtin_amdgcn_global_load_lds(                                            \
      (const __attribute__((address_space(1))) void*)(gp),                     \
      (__attribute__((address_space(3))) void*)(lp), 16, 0, 0)

// ---------------------------------------------------------------------------
// fp32 -> bf16 hi + residual lo (RNE), fused with row squared-norm.
// ---------------------------------------------------------------------------
__device__ __forceinline__ unsigned bf_rne(float x) {
  unsigned u = __float_as_uint(x);
  return (u + 0x7fffu + ((u >> 16) & 1u)) >> 16;
}

__global__ __launch_bounds__(256) void prep_kernel(
    const float* __restrict__ X, short* __restrict__ hi,
    short* __restrict__ lo, float* __restrict__ sq, int nrows) {
  const int wave = threadIdx.x >> 6;
  const int lane = threadIdx.x & 63;
  const int row = blockIdx.x * 4 + wave;
  if (row >= nrows) return;
  const float* xr = X + (size_t)row * D_DIM;
  float4 x0 = ((const float4*)xr)[lane * 2];
  float4 x1 = ((const float4*)xr)[lane * 2 + 1];
  float xs[8] = {x0.x, x0.y, x0.z, x0.w, x1.x, x1.y, x1.z, x1.w};
  union { short s[8]; int4 v; } H, L;
  float ssum = 0.f;
  #pragma unroll
  for (int j = 0; j < 8; ++j) {
    unsigned rh = bf_rne(xs[j]);
    H.s[j] = (short)rh;
    float h = __uint_as_float(rh << 16);
    L.s[j] = (short)bf_rne(xs[j] - h);
    ssum += xs[j] * xs[j];
  }
  *(int4*)(hi + (size_t)row * D_DIM + lane * 8) = H.v;
  *(int4*)(lo + (size_t)row * D_DIM + lane * 8) = L.v;
  #pragma unroll
  for (int o = 32; o > 0; o >>= 1) ssum += __shfl_xor(ssum, o, 64);
  if (lane == 0) sq[row] = ssum;
}

// ---------------------------------------------------------------------------
// Stage 1: persistent-z hi*hi top-2 argmin, barrier-free k-loop.
// V6: R5 post-mortem -- the staggered sweep destroyed lockstep L2 locality
// (FETCH 50MB -> 6.5GB) and the added pressure spilled (WRITE 908MB of
// scratch). REVERTED both. This round isolates ONE variable vs R4: B-load
// pipeline depth 1 -> 3 (4 rotating register slots, statically indexed via
// full unroll of the dc loop; slot = lg&3, phase-consistent across k-tiles
// since 16 % 4 == 0). Lockstep ascending sweep restored (keeps W L2-hot and
// strict `<` argmin = lowest-index-on-ties). Arch-VGPR budget ~108 < 128 cap
// at 4 waves/SIMD (acc in AGPRs): no spill expected.
// ---------------------------------------------------------------------------
__global__ __launch_bounds__(512, 4) void stage1_kernel(
    const short* __restrict__ zhi, const short* __restrict__ whi,
    const float* __restrict__ wsq, float* __restrict__ cv1,
    int* __restrict__ ci1, float* __restrict__ cv2) {
  __shared__ short Zt[32768];   // 64 KB: [dc 0..63][row 0..63][8 bf16]
  float* rv1 = (float*)Zt;             // post-loop overlay: [64][8] f32 (2 KB)
  int*   ri1 = (int*)(Zt + 1024);      // +2 KB
  float* rv2 = (float*)(Zt + 2048);    // +4 KB

  const int tid = threadIdx.x;
  const int lane = tid & 63;
  const int wave = tid >> 6;     // 0..7 = code slice (wn)
  const int l15 = lane & 15, l4 = lane >> 4;
  const int row0 = blockIdx.x * 64;

  // one-time z-tile load (slot = dc*64 + row; LDS dest = slot*16 B)
  #pragma unroll
  for (int j = 0; j < 8; ++j) {
    const int slot = j * 512 + tid;
    const int r = slot & 63, dc = slot >> 6;
    GLL16(zhi + (size_t)(row0 + r) * D_DIM + dc * 8, Zt + (size_t)slot * 8);
  }

  // per-lane B base pointers: code = wave*32 + cb*16 + l15, d-subchunk = l4*8
  const short* pb[2];
  #pragma unroll
  for (int cb = 0; cb < 2; ++cb)
    pb[cb] = whi + (size_t)(wave * 32 + cb * 16 + l15) * D_DIM + l4 * 8;

  float v1[16], v2[16];
  int   i1[16];
  #pragma unroll
  for (int s = 0; s < 16; ++s) { v1[s] = INFINITY; v2[s] = INFINITY; i1[s] = 0x7fffffff; }

  // B register pipeline: 4 slots, 3 chunks in flight.
  // chunk lg (0..511 ascending): element offset = (tile)*256*D + (lg&15)*32,
  // tile wraps &31 so the tail's lg+3 dummy prefetches stay in-bounds.
  bf16x8 bp[4][2];
  #pragma unroll
  for (int p = 0; p < 3; ++p) {
    const size_t o0 = (size_t)((p & 15) * 32);   // tile 0, chunks 0..2
    #pragma unroll
    for (int cb = 0; cb < 2; ++cb) bp[p][cb] = *(const bf16x8*)(pb[cb] + o0);
  }

  __syncthreads();  // z-tile DMA complete & visible; the ONLY pre-loop barrier

  for (int t = 0; t < 32; ++t) {
    const int ktc = t << 8;                  // code base of current tile
    f32x4 acc[4][2];
    #pragma unroll
    for (int rb = 0; rb < 4; ++rb)
      #pragma unroll
      for (int cb = 0; cb < 2; ++cb) acc[rb][cb] = (f32x4)0.f;

    #pragma unroll
    for (int dc = 0; dc < 16; ++dc) {
      const int lg = t * 16 + dc;
      // A fragments for current chunk (persistent z-tile in LDS)
      bf16x8 a[4];
      #pragma unroll
      for (int rb = 0; rb < 4; ++rb)
        a[rb] = *(const bf16x8*)&Zt[((dc * 4 + l4) * 64 + rb * 16 + l15) * 8];
      // issue B loads 3 chunks ahead into slot (dc+3)&3 (static after unroll)
      {
        const int lg3 = lg + 3;
        const size_t o3 = (size_t)(((lg3 >> 4) & 31) * 256) * D_DIM
                        + (size_t)((lg3 & 15) * 32);
        #pragma unroll
        for (int cb = 0; cb < 2; ++cb)
          bp[(dc + 3) & 3][cb] = *(const bf16x8*)(pb[cb] + o3);
      }
      // MFMA consumes slot dc&3 (loaded 3 chunks ago)
      #pragma unroll
      for (int rb = 0; rb < 4; ++rb)
        #pragma unroll
        for (int cb = 0; cb < 2; ++cb)
          acc[rb][cb] = __builtin_amdgcn_mfma_f32_16x16x32_bf16(
              a[rb], bp[dc & 3][cb], acc[rb][cb], 0, 0, 0);
    }

    // score 256-code tile; C/D layout: col=lane&15, row=(lane>>4)*4+reg.
    // ascending sweep -> strict `<` keeps the lowest index on ties.
    #pragma unroll
    for (int cb = 0; cb < 2; ++cb) {
      const int col = ktc + wave * 32 + cb * 16 + l15;
      const float wv = wsq[col];
      #pragma unroll
      for (int rb = 0; rb < 4; ++rb) {
        f32x4 a = acc[rb][cb];
        #pragma unroll
        for (int rg = 0; rg < 4; ++rg) {
          const float dist = wv - 2.0f * a[rg];
          const int s = rb * 4 + rg;
          if (dist < v1[s]) {
            v2[s] = v1[s]; v1[s] = dist; i1[s] = col;
          } else {
            v2[s] = fminf(v2[s], dist);
          }
        }
      }
    }
  }

  // in-register top-2 merge across the 16 col-classes (lanes l4*16 .. +15
  // all hold the same physical rows; xor masks 1,2,4,8 stay in-group).
  __syncthreads();  // compute done; Zt dead -> overlay
  #pragma unroll
  for (int s = 0; s < 16; ++s) {
    float a1 = v1[s], a2 = v2[s];
    int ai = i1[s];
    #pragma unroll
    for (int m = 1; m < 16; m <<= 1) {
      const float b1 = __shfl_xor(a1, m, 64);
      const float b2 = __shfl_xor(a2, m, 64);
      const int   bi = __shfl_xor(ai, m, 64);
      if (b1 < a1 || (b1 == a1 && bi < ai)) {
        a2 = fminf(a1, b2); a1 = b1; ai = bi;
      } else {
        a2 = fminf(a2, b1);
      }
    }
    if (l15 == 0) {
      const int r = (s >> 2) * 16 + l4 * 4 + (s & 3);
      rv1[r * 8 + wave] = a1;
      ri1[r * 8 + wave] = ai;
      rv2[r * 8 + wave] = a2;
    }
  }
  __syncthreads();

  if (tid < 64) {
    float V1 = INFINITY, V2 = INFINITY;
    int I1 = 0x7fffffff;
    #pragma unroll
    for (int w = 0; w < 8; ++w) {
      const float a1 = rv1[tid * 8 + w];
      const int ai = ri1[tid * 8 + w];
      const float a2 = rv2[tid * 8 + w];
      if (a1 < V1 || (a1 == V1 && ai < I1)) {
        V2 = fminf(V1, a2); V1 = a1; I1 = ai;
      } else {
        V2 = fminf(V2, a1);
      }
    }
    cv1[row0 + tid] = V1; ci1[row0 + tid] = I1; cv2[row0 + tid] = V2;
  }
}

// ---------------------------------------------------------------------------
// Commit unambiguous rows; compact ambiguous rows into refine list.
// ---------------------------------------------------------------------------
__global__ __launch_bounds__(256) void merge_flag_kernel(
    const float* __restrict__ cv1, const int* __restrict__ ci1,
    const float* __restrict__ cv2, int* __restrict__ idx,
    float* __restrict__ out_idx_f, int* __restrict__ hist,
    unsigned long long* __restrict__ packed, int* __restrict__ cnt,
    int* __restrict__ list) {
  const int row = blockIdx.x * 256 + threadIdx.x;
  const float V1 = cv1[row];
  const int I1 = ci1[row];
  const float V2 = cv2[row];
  if (V2 - V1 >= EPS) {
    idx[row] = I1;
    out_idx_f[row] = (float)I1;
    atomicAdd(&hist[I1], 1);
  } else {
    packed[row] = 0xffffffffffffffffULL;
    const int p = atomicAdd(cnt, 1);
    list[p] = row;
  }
}

// ---------------------------------------------------------------------------
// Refine: exact 3-pass distance argmin over ALL codes for flagged rows.
// Split-K=16, merged via packed atomicMin (value-then-lowest-idx order).
// ---------------------------------------------------------------------------
__global__ __launch_bounds__(256, 2) void refine_kernel(
    const short* __restrict__ zhi, const short* __restrict__ zlo,
    const short* __restrict__ whi, const short* __restrict__ wlo,
    const float* __restrict__ zz, const float* __restrict__ wsq,
    const int* __restrict__ cnt, const int* __restrict__ list,
    unsigned long long* __restrict__ packed) {
  __shared__ char smem[32768];
  short* Ah = (short*)smem;
  short* Al = (short*)(smem + 8192);
  short* Bh = (short*)(smem + 16384);
  short* Bl = (short*)(smem + 24576);
  float* rv = (float*)smem;
  int*   ri = (int*)(smem + 16384);

  const int n = *cnt;
  const int bx = blockIdx.x;
  const int rt = bx >> 4;
  const int ks = bx & 15;
  if (rt * BMT >= n) return;
  const int k0 = ks * KRANGE_R;

  const int tid = threadIdx.x;
  const int lane = tid & 63;
  const int wave = tid >> 6;
  const int wm = wave >> 1, wn = wave & 1;
  const int l15 = lane & 15, l4 = lane >> 4;

  const int r0s = tid & 127;
  const int kc0 = tid >> 7;
  const int kc1 = kc0 + 2;
  const int rowg = list[min(rt * BMT + r0s, n - 1)];

  float zzr[16];
  #pragma unroll
  for (int rb = 0; rb < 4; ++rb)
    #pragma unroll
    for (int rg = 0; rg < 4; ++rg) {
      const int m = wm * 64 + rb * 16 + l4 * 4 + rg;
      zzr[rb * 4 + rg] = zz[list[min(rt * BMT + m, n - 1)]];
    }

  float best[16];
  int   bidx[16];
  #pragma unroll
  for (int s = 0; s < 16; ++s) { best[s] = INFINITY; bidx[s] = 0x7fffffff; }

  for (int kt = 0; kt < KRANGE_R; kt += BNT) {
    f32x4 acc[4][4];
    #pragma unroll
    for (int rb = 0; rb < 4; ++rb)
      #pragma unroll
      for (int cb = 0; cb < 4; ++cb) acc[rb][cb] = (f32x4)0.f;

    for (int d0 = 0; d0 < D_DIM; d0 += 32) {
      const size_t ga0 = (size_t)rowg * D_DIM + d0 + kc0 * 8;
      const size_t ga1 = (size_t)rowg * D_DIM + d0 + kc1 * 8;
      const size_t gb0 = (size_t)(k0 + kt + r0s) * D_DIM + d0 + kc0 * 8;
      const size_t gb1 = (size_t)(k0 + kt + r0s) * D_DIM + d0 + kc1 * 8;
      GLL16(zhi + ga0, Ah + (size_t)tid * 8);
      GLL16(zhi + ga1, Ah + (size_t)(tid + 256) * 8);
      GLL16(zlo + ga0, Al + (size_t)tid * 8);
      GLL16(zlo + ga1, Al + (size_t)(tid + 256) * 8);
      GLL16(whi + gb0, Bh + (size_t)tid * 8);
      GLL16(whi + gb1, Bh + (size_t)(tid + 256) * 8);
      GLL16(wlo + gb0, Bl + (size_t)tid * 8);
      GLL16(wlo + gb1, Bl + (size_t)(tid + 256) * 8);
      __syncthreads();

      bf16x8 ah[4], al[4], bh[4], bl[4];
      #pragma unroll
      for (int rb = 0; rb < 4; ++rb) {
        const int m = wm * 64 + rb * 16 + l15;
        ah[rb] = *(const bf16x8*)&Ah[(l4 * 128 + m) * 8];
        al[rb] = *(const bf16x8*)&Al[(l4 * 128 + m) * 8];
      }
      #pragma unroll
      for (int cb = 0; cb < 4; ++cb) {
        const int nn = wn * 64 + cb * 16 + l15;
        bh[cb] = *(const bf16x8*)&Bh[(l4 * 128 + nn) * 8];
        bl[cb] = *(const bf16x8*)&Bl[(l4 * 128 + nn) * 8];
      }
      #pragma unroll
      for (int rb = 0; rb < 4; ++rb)
        #pragma unroll
        for (int cb = 0; cb < 4; ++cb) {
          acc[rb][cb] = __builtin_amdgcn_mfma_f32_16x16x32_bf16(
              ah[rb], bh[cb], acc[rb][cb], 0, 0, 0);
          acc[rb][cb] = __builtin_amdgcn_mfma_f32_16x16x32_bf16(
              ah[rb], bl[cb], acc[rb][cb], 0, 0, 0);
          acc[rb][cb] = __builtin_amdgcn_mfma_f32_16x16x32_bf16(
              al[rb], bh[cb], acc[rb][cb], 0, 0, 0);
        }
      __syncthreads();
    }

    #pragma unroll
    for (int cb = 0; cb < 4; ++cb) {
      const int col = k0 + kt + wn * 64 + cb * 16 + l15;
      const float wv = wsq[col];
      #pragma unroll
      for (int rb = 0; rb < 4; ++rb) {
        f32x4 a = acc[rb][cb];
        #pragma unroll
        for (int rg = 0; rg < 4; ++rg) {
          const float dist = (zzr[rb * 4 + rg] + wv) - 2.0f * a[rg];
          const int s = rb * 4 + rg;
          if (dist < best[s]) { best[s] = dist; bidx[s] = col; }
        }
      }
    }
  }

  #pragma unroll
  for (int rb = 0; rb < 4; ++rb)
    #pragma unroll
    for (int rg = 0; rg < 4; ++rg) {
      const int s = rb * 4 + rg;
      const int R = wm * 64 + rb * 16 + l4 * 4 + rg;
      rv[R * 32 + wn * 16 + l15] = best[s];
      ri[R * 32 + wn * 16 + l15] = bidx[s];
    }
  __syncthreads();

  if (tid < BMT && rt * BMT + tid < n) {
    float bv = INFINITY;
    int bi = 0x7fffffff;
    #pragma unroll
    for (int t = 0; t < 32; ++t) {
      const float v = rv[tid * 32 + t];
      const int ix = ri[tid * 32 + t];
      if (v < bv || (v == bv && ix < bi)) { bv = v; bi = ix; }
    }
    const int row = list[rt * BMT + tid];
    const unsigned long long pk =
        ((unsigned long long)__float_as_uint(bv) << 32) | (unsigned)bi;
    atomicMin(&packed[row], pk);
  }
}

// ---------------------------------------------------------------------------
__global__ __launch_bounds__(256) void final_merge_kernel(
    const int* __restrict__ cnt, const int* __restrict__ list,
    const unsigned long long* __restrict__ packed, int* __restrict__ idx,
    float* __restrict__ out_idx_f, int* __restrict__ hist) {
  const int t = blockIdx.x * 256 + threadIdx.x;
  if (t >= *cnt) return;
  const int row = list[t];
  const int bi = (int)(packed[row] & 0xffffffffULL);
  idx[row] = bi;
  out_idx_f[row] = (float)bi;
  atomicAdd(&hist[bi], 1);
}

// ---------------------------------------------------------------------------
// Gather + straight-through + per-block MSE partial (no global atomics).
// ---------------------------------------------------------------------------
__global__ __launch_bounds__(256) void gather_kernel(
    const float* __restrict__ z, const float* __restrict__ W,
    const int* __restrict__ idx, float* __restrict__ out,
    double* __restrict__ mse_part) {
  __shared__ float wsum[4];
  const int wave = threadIdx.x >> 6;
  const int lane = threadIdx.x & 63;
  const int row = blockIdx.x * 4 + wave;
  const int k = idx[row];
  const float* zr = z + (size_t)row * D_DIM;
  const float* wr = W + (size_t)k * D_DIM;
  float* outr = out + (size_t)row * D_DIM;
  float s = 0.f;
  #pragma unroll
  for (int h = 0; h < 2; ++h) {
    const int c = h * 256 + lane * 4;
    float4 zv = *(const float4*)(zr + c);
    float4 qv = *(const float4*)(wr + c);
    float4 st;
    st.x = zv.x + (qv.x - zv.x);
    st.y = zv.y + (qv.y - zv.y);
    st.z = zv.z + (qv.z - zv.z);
    st.w = zv.w + (qv.w - zv.w);
    float dx = zv.x - qv.x, dy = zv.y - qv.y, dz = zv.z - qv.z, dw = zv.w - qv.w;
    s += dx * dx + dy * dy + dz * dz + dw * dw;
    *(float4*)(outr + c) = st;
  }
  #pragma unroll
  for (int o = 32; o > 0; o >>= 1) s += __shfl_xor(s, o, 64);
  if (lane == 0) wsum[wave] = s;
  __syncthreads();
  if (threadIdx.x == 0)
    mse_part[blockIdx.x] =
        (double)wsum[0] + (double)wsum[1] + (double)wsum[2] + (double)wsum[3];
}

// ---------------------------------------------------------------------------
// Loss: entropy over histogram + MSE partial-sum reduction (8192 partials
// == K_EMB, so both fold into the same strided loop).
// ---------------------------------------------------------------------------
__global__ __launch_bounds__(256) void loss_kernel(
    const int* __restrict__ hist, const double* __restrict__ mse_part,
    float* __restrict__ out_loss) {
  __shared__ float ls[4];
  __shared__ double ld[4];
  const int tid = threadIdx.x;
  float e = 0.f;
  double ms = 0.0;
  for (int b = tid; b < K_EMB; b += 256) {
    float p = (float)hist[b] * (1.0f / 32768.0f);
    e += p * logf(p + 1e-10f);
    ms += mse_part[b];
  }
  #pragma unroll
  for (int o = 32; o > 0; o >>= 1) {
    e += __shfl_xor(e, o, 64);
    ms += __shfl_xor(ms, o, 64);
  }
  if ((tid & 63) == 0) { ls[tid >> 6] = e; ld[tid >> 6] = ms; }
  __syncthreads();
  if (tid == 0) {
    float entropy = -(ls[0] + ls[1] + ls[2] + ls[3]);
    float mse = (float)((ld[0] + ld[1] + ld[2] + ld[3]) / 16777216.0);
    float entropy_loss = 1.0f - entropy / logf(8192.0f);
    out_loss[0] = mse + 0.25f * mse + 0.1f * entropy_loss;
  }
}

// ---------------------------------------------------------------------------
extern "C" void kernel_launch(void* const* d_in, const int* in_sizes, int n_in,
                              void* d_out, int out_size, void* d_ws, size_t ws_size,
                              hipStream_t stream) {
  const float* z = (const float*)d_in[0];  // [32768,512]
  const float* W = (const float*)d_in[1];  // [8192,512]
  float* out = (float*)d_out;              // [B*D] st | [1] loss | [B] indices

  char* ws = (char*)d_ws;
  int*    cnt     = (int*)(ws + 8);                        // @8
  int*    hist    = (int*)(ws + 4096);                     // 32 KB
  unsigned long long* packed = (unsigned long long*)(ws + 65536);  // 256 KB
  float*  zz   = (float*)(ws + 327680);                    // 128 KB
  float*  wsq  = (float*)(ws + 458752);                    // 32 KB
  int*    idx  = (int*)(ws + 491520);                      // 128 KB
  int*    list = (int*)(ws + 622592);                      // 128 KB
  float*  cv1  = (float*)(ws + 786432);                    // [B_ROWS]
  int*    ci1  = (int*)(ws + 1310720);                     // [B_ROWS]
  float*  cv2  = (float*)(ws + 1835008);                   // [B_ROWS]
  double* mse_part = (double*)(ws + 2097152);              // 64 KB [8192]
  short*  zhi  = (short*)(ws + 4194304);                   // 32 MB
  short*  zlo  = (short*)(ws + 37748736);                  // 32 MB
  short*  whi  = (short*)(ws + 71303168);                  // 8 MB
  short*  wlo  = (short*)(ws + 79691776);                  // 8 MB (ends 84 MB)

  hipMemsetAsync(d_ws, 0, 36864, stream);  // cnt + hist

  prep_kernel<<<B_ROWS / 4, 256, 0, stream>>>(z, zhi, zlo, zz, B_ROWS);
  prep_kernel<<<K_EMB / 4, 256, 0, stream>>>(W, whi, wlo, wsq, K_EMB);

  stage1_kernel<<<B_ROWS / 64, 512, 0, stream>>>(zhi, whi, wsq, cv1, ci1, cv2);

  merge_flag_kernel<<<B_ROWS / 256, 256, 0, stream>>>(
      cv1, ci1, cv2, idx, out + (size_t)B_ROWS * D_DIM + 1, hist,
      packed, cnt, list);

  refine_kernel<<<(B_ROWS / BMT) * RSPLIT, 256, 0, stream>>>(
      zhi, zlo, whi, wlo, zz, wsq, cnt, list, packed);

  final_merge_kernel<<<B_ROWS / 256, 256, 0, stream>>>(
      cnt, list, packed, idx, out + (size_t)B_ROWS * D_DIM + 1, hist);

  gather_kernel<<<B_ROWS / 4, 256, 0, stream>>>(z, W, idx, out, mse_part);

  loss_kernel<<<1, 256, 0, stream>>>(hist, mse_part,
                                     out + (size_t)B_ROWS * D_DIM);
}

// Round 7
// 1364.832 us; speedup vs baseline: 2.0156x; 1.3602x over previous
//
#include <hip/hip_runtime.h>
#include <math.h>

#define B_ROWS 32768
#define D_DIM  512
#define K_EMB  8192

#define BMT 128
#define BNT 128
#define RSPLIT 16
#define KRANGE_R (K_EMB / RSPLIT)   // 512
#define EPS 0.10f

#define S1_NG  4     // code groups (2048 codes each)
#define S1_TPG 16    // 128-code tiles per group

typedef __attribute__((ext_vector_type(4))) float f32x4;
typedef __attribute__((ext_vector_type(8))) short bf16x8;

#define GLL16(gp, lp)                                                          \
  __builtin_amdgcn_global_load_lds(                                            \
      (const __attribute__((address_space(1))) void*)(gp),                     \
      (__attribute__((address_space(3))) void*)(lp), 16, 0, 0)

// ---------------------------------------------------------------------------
// fp32 -> bf16 hi + residual lo (RNE), fused with row squared-norm.
// ---------------------------------------------------------------------------
__device__ __forceinline__ unsigned bf_rne(float x) {
  unsigned u = __float_as_uint(x);
  return (u + 0x7fffu + ((u >> 16) & 1u)) >> 16;
}

__global__ __launch_bounds__(256) void prep_kernel(
    const float* __restrict__ X, short* __restrict__ hi,
    short* __restrict__ lo, float* __restrict__ sq, int nrows) {
  const int wave = threadIdx.x >> 6;
  const int lane = threadIdx.x & 63;
  const int row = blockIdx.x * 4 + wave;
  if (row >= nrows) return;
  const float* xr = X + (size_t)row * D_DIM;
  float4 x0 = ((const float4*)xr)[lane * 2];
  float4 x1 = ((const float4*)xr)[lane * 2 + 1];
  float xs[8] = {x0.x, x0.y, x0.z, x0.w, x1.x, x1.y, x1.z, x1.w};
  union { short s[8]; int4 v; } H, L;
  float ssum = 0.f;
  #pragma unroll
  for (int j = 0; j < 8; ++j) {
    unsigned rh = bf_rne(xs[j]);
    H.s[j] = (short)rh;
    float h = __uint_as_float(rh << 16);
    L.s[j] = (short)bf_rne(xs[j] - h);
    ssum += xs[j] * xs[j];
  }
  *(int4*)(hi + (size_t)row * D_DIM + lane * 8) = H.v;
  *(int4*)(lo + (size_t)row * D_DIM + lane * 8) = L.v;
  #pragma unroll
  for (int o = 32; o > 0; o >>= 1) ssum += __shfl_xor(ssum, o, 64);
  if (lane == 0) sq[row] = ssum;
}

// ---------------------------------------------------------------------------
// Stage 1 V7: m97-structure GEMM (guide-verified 874-912 TF on this chip)
// with fused per-tile top-2 epilogue. Replaces the persistent-z design whose
// per-wave W register streams hit an L2 same-line service wall (~1024
// wave-loads/chunk/XCD, invariant R1=R4) and spilled whenever the pipeline
// deepened (top-2 state + acc + B-stream all live across the K-sweep).
// Here: 128x128 tile, BK=32, 256 thr / 4 waves, global_load_lds stages BOTH
// operands (each W line fetched once per block, no B registers), 2 barriers
// per K-step, >=3 blocks/CU overlap the barrier drains. Top-2 state lives
// only in the short per-tile epilogue (full distance tile is in acc first).
// Inner loop (LDS layout, frag mapping, MFMA) lifted verbatim from
// refine_kernel, which passes the harness today. Grid = 256 mtiles x 4 code
// groups; block sweeps its group's 16 tiles; XCD-bijective swizzle (nwg%8==0)
// keeps each group's W panels resident in 2 XCDs' L2.
// K-order ascending 32-d chunks == old stage1 -> bit-identical proxy dots;
// tie-breaks (lowest code index) preserved at every merge level.
// ---------------------------------------------------------------------------
__global__ __launch_bounds__(256, 3) void stage1_gemm(
    const short* __restrict__ zhi, const short* __restrict__ whi,
    const float* __restrict__ wsq, float* __restrict__ cgv1,
    int* __restrict__ cgi1, float* __restrict__ cgv2) {
  __shared__ short As[4096];     // 8 KB: [dsub 0..3][row 0..127][8 bf16]
  __shared__ short Bs[4096];     // 8 KB: [dsub 0..3][code 0..127][8 bf16]
  __shared__ float ctv1[256];    // per-tile cand: [row][wn]
  __shared__ int   cti1[256];
  __shared__ float ctv2[256];

  const int tid = threadIdx.x;
  const int lane = tid & 63;
  const int wave = tid >> 6;          // 0..3
  const int wm = wave >> 1, wn = wave & 1;
  const int l15 = lane & 15, l4 = lane >> 4;

  // XCD swizzle: nwg = 1024 (divisible by 8) -> bijective
  const int wg = ((blockIdx.x & 7) << 7) | (blockIdx.x >> 3);
  const int g = wg >> 8;              // code group 0..3
  const int mt = wg & 255;            // row tile 0..255
  const int row0 = mt * 128;

  const int r_st = tid & 127;         // staging row/code
  const int d_st = tid >> 7;          // staging d-sub 0..1 (and +2)

  float rv1 = INFINITY, rv2 = INFINITY;   // running top-2 (threads < 128)
  int   ri1 = 0x7fffffff;

  for (int nt = 0; nt < S1_TPG; ++nt) {
    const int kb = (g * S1_TPG + nt) * 128;   // code base of this tile
    f32x4 acc[4][4];
    #pragma unroll
    for (int rb = 0; rb < 4; ++rb)
      #pragma unroll
      for (int cb = 0; cb < 4; ++cb) acc[rb][cb] = (f32x4)0.f;

    for (int ks = 0; ks < 16; ++ks) {
      const int d0 = ks * 32;
      const size_t ga = (size_t)(row0 + r_st) * D_DIM + d0 + d_st * 8;
      const size_t gb = (size_t)(kb + r_st) * D_DIM + d0 + d_st * 8;
      GLL16(zhi + ga,      As + (size_t)tid * 8);
      GLL16(zhi + ga + 16, As + (size_t)(tid + 256) * 8);
      GLL16(whi + gb,      Bs + (size_t)tid * 8);
      GLL16(whi + gb + 16, Bs + (size_t)(tid + 256) * 8);
      __syncthreads();   // DMA drained: tiles visible

      bf16x8 a[4], b[4];
      #pragma unroll
      for (int rb = 0; rb < 4; ++rb)
        a[rb] = *(const bf16x8*)&As[(l4 * 128 + wm * 64 + rb * 16 + l15) * 8];
      #pragma unroll
      for (int cb = 0; cb < 4; ++cb)
        b[cb] = *(const bf16x8*)&Bs[(l4 * 128 + wn * 64 + cb * 16 + l15) * 8];
      #pragma unroll
      for (int rb = 0; rb < 4; ++rb)
        #pragma unroll
        for (int cb = 0; cb < 4; ++cb)
          acc[rb][cb] = __builtin_amdgcn_mfma_f32_16x16x32_bf16(
              a[rb], b[cb], acc[rb][cb], 0, 0, 0);
      __syncthreads();   // reads done before next chunk's DMA overwrites
    }

    // ---- epilogue: top-2 over this tile's 128 codes ----
    // C/D layout: col = lane&15 (+cb*16+wn*64), row = (lane>>4)*4 + rg.
    float wvv[4]; int colv[4];
    #pragma unroll
    for (int cb = 0; cb < 4; ++cb) {
      colv[cb] = kb + wn * 64 + cb * 16 + l15;
      wvv[cb] = wsq[colv[cb]];
    }
    #pragma unroll
    for (int rb = 0; rb < 4; ++rb)
      #pragma unroll
      for (int rg = 0; rg < 4; ++rg) {
        float tv1 = INFINITY, tv2 = INFINITY;
        int ti1 = 0x7fffffff;
        #pragma unroll
        for (int cb = 0; cb < 4; ++cb) {      // cb ascending = cols ascending
          const float dist = wvv[cb] - 2.0f * acc[rb][cb][rg];
          if (dist < tv1) { tv2 = tv1; tv1 = dist; ti1 = colv[cb]; }
          else tv2 = fminf(tv2, dist);
        }
        #pragma unroll
        for (int m = 1; m < 16; m <<= 1) {    // merge across l15 group
          const float b1 = __shfl_xor(tv1, m, 64);
          const float b2 = __shfl_xor(tv2, m, 64);
          const int   bi = __shfl_xor(ti1, m, 64);
          if (b1 < tv1 || (b1 == tv1 && bi < ti1)) {
            tv2 = fminf(tv1, b2); tv1 = b1; ti1 = bi;
          } else {
            tv2 = fminf(tv2, b1);
          }
        }
        if (l15 == 0) {
          const int r = wm * 64 + rb * 16 + l4 * 4 + rg;
          ctv1[r * 2 + wn] = tv1;
          cti1[r * 2 + wn] = ti1;
          ctv2[r * 2 + wn] = tv2;
        }
      }
    __syncthreads();
    if (tid < 128) {
      // merge wn=0 (cols 0..63) then wn=1 into running top-2 (ascending order)
      #pragma unroll
      for (int h = 0; h < 2; ++h) {
        const float b1 = ctv1[tid * 2 + h];
        const float b2 = ctv2[tid * 2 + h];
        const int   bi = cti1[tid * 2 + h];
        if (b1 < rv1 || (b1 == rv1 && bi < ri1)) {
          rv2 = fminf(rv1, b2); rv1 = b1; ri1 = bi;
        } else {
          rv2 = fminf(rv2, b1);
        }
      }
    }
    __syncthreads();
  }

  if (tid < 128) {
    const int o = (row0 + tid) * S1_NG + g;
    cgv1[o] = rv1; cgi1[o] = ri1; cgv2[o] = rv2;
  }
}

// ---------------------------------------------------------------------------
// Merge the 4 per-group candidates per row (groups ascending in code index,
// so tie-break = keep earlier). Vectorized float4/int4 reads.
// ---------------------------------------------------------------------------
__global__ __launch_bounds__(256) void merge_groups_kernel(
    const float* __restrict__ cgv1, const int* __restrict__ cgi1,
    const float* __restrict__ cgv2, float* __restrict__ cv1,
    int* __restrict__ ci1, float* __restrict__ cv2) {
  const int row = blockIdx.x * 256 + threadIdx.x;
  const float4 q1 = ((const float4*)cgv1)[row];
  const int4   qi = ((const int4*)cgi1)[row];
  const float4 q2 = ((const float4*)cgv2)[row];
  float V1 = q1.x, V2 = q2.x;
  int I1 = qi.x;
  const float b1s[3] = {q1.y, q1.z, q1.w};
  const float b2s[3] = {q2.y, q2.z, q2.w};
  const int   bis[3] = {qi.y, qi.z, qi.w};
  #pragma unroll
  for (int gg = 0; gg < 3; ++gg) {
    const float b1 = b1s[gg], b2 = b2s[gg];
    const int bi = bis[gg];
    if (b1 < V1 || (b1 == V1 && bi < I1)) {
      V2 = fminf(V1, b2); V1 = b1; I1 = bi;
    } else {
      V2 = fminf(V2, b1);
    }
  }
  cv1[row] = V1; ci1[row] = I1; cv2[row] = V2;
}

// ---------------------------------------------------------------------------
// Commit unambiguous rows; compact ambiguous rows into refine list.
// ---------------------------------------------------------------------------
__global__ __launch_bounds__(256) void merge_flag_kernel(
    const float* __restrict__ cv1, const int* __restrict__ ci1,
    const float* __restrict__ cv2, int* __restrict__ idx,
    float* __restrict__ out_idx_f, int* __restrict__ hist,
    unsigned long long* __restrict__ packed, int* __restrict__ cnt,
    int* __restrict__ list) {
  const int row = blockIdx.x * 256 + threadIdx.x;
  const float V1 = cv1[row];
  const int I1 = ci1[row];
  const float V2 = cv2[row];
  if (V2 - V1 >= EPS) {
    idx[row] = I1;
    out_idx_f[row] = (float)I1;
    atomicAdd(&hist[I1], 1);
  } else {
    packed[row] = 0xffffffffffffffffULL;
    const int p = atomicAdd(cnt, 1);
    list[p] = row;
  }
}

// ---------------------------------------------------------------------------
// Refine: exact 3-pass distance argmin over ALL codes for flagged rows.
// Split-K=16, merged via packed atomicMin (value-then-lowest-idx order).
// ---------------------------------------------------------------------------
__global__ __launch_bounds__(256, 2) void refine_kernel(
    const short* __restrict__ zhi, const short* __restrict__ zlo,
    const short* __restrict__ whi, const short* __restrict__ wlo,
    const float* __restrict__ zz, const float* __restrict__ wsq,
    const int* __restrict__ cnt, const int* __restrict__ list,
    unsigned long long* __restrict__ packed) {
  __shared__ char smem[32768];
  short* Ah = (short*)smem;
  short* Al = (short*)(smem + 8192);
  short* Bh = (short*)(smem + 16384);
  short* Bl = (short*)(smem + 24576);
  float* rv = (float*)smem;
  int*   ri = (int*)(smem + 16384);

  const int n = *cnt;
  const int bx = blockIdx.x;
  const int rt = bx >> 4;
  const int ks = bx & 15;
  if (rt * BMT >= n) return;
  const int k0 = ks * KRANGE_R;

  const int tid = threadIdx.x;
  const int lane = tid & 63;
  const int wave = tid >> 6;
  const int wm = wave >> 1, wn = wave & 1;
  const int l15 = lane & 15, l4 = lane >> 4;

  const int r0s = tid & 127;
  const int kc0 = tid >> 7;
  const int kc1 = kc0 + 2;
  const int rowg = list[min(rt * BMT + r0s, n - 1)];

  float zzr[16];
  #pragma unroll
  for (int rb = 0; rb < 4; ++rb)
    #pragma unroll
    for (int rg = 0; rg < 4; ++rg) {
      const int m = wm * 64 + rb * 16 + l4 * 4 + rg;
      zzr[rb * 4 + rg] = zz[list[min(rt * BMT + m, n - 1)]];
    }

  float best[16];
  int   bidx[16];
  #pragma unroll
  for (int s = 0; s < 16; ++s) { best[s] = INFINITY; bidx[s] = 0x7fffffff; }

  for (int kt = 0; kt < KRANGE_R; kt += BNT) {
    f32x4 acc[4][4];
    #pragma unroll
    for (int rb = 0; rb < 4; ++rb)
      #pragma unroll
      for (int cb = 0; cb < 4; ++cb) acc[rb][cb] = (f32x4)0.f;

    for (int d0 = 0; d0 < D_DIM; d0 += 32) {
      const size_t ga0 = (size_t)rowg * D_DIM + d0 + kc0 * 8;
      const size_t ga1 = (size_t)rowg * D_DIM + d0 + kc1 * 8;
      const size_t gb0 = (size_t)(k0 + kt + r0s) * D_DIM + d0 + kc0 * 8;
      const size_t gb1 = (size_t)(k0 + kt + r0s) * D_DIM + d0 + kc1 * 8;
      GLL16(zhi + ga0, Ah + (size_t)tid * 8);
      GLL16(zhi + ga1, Ah + (size_t)(tid + 256) * 8);
      GLL16(zlo + ga0, Al + (size_t)tid * 8);
      GLL16(zlo + ga1, Al + (size_t)(tid + 256) * 8);
      GLL16(whi + gb0, Bh + (size_t)tid * 8);
      GLL16(whi + gb1, Bh + (size_t)(tid + 256) * 8);
      GLL16(wlo + gb0, Bl + (size_t)tid * 8);
      GLL16(wlo + gb1, Bl + (size_t)(tid + 256) * 8);
      __syncthreads();

      bf16x8 ah[4], al[4], bh[4], bl[4];
      #pragma unroll
      for (int rb = 0; rb < 4; ++rb) {
        const int m = wm * 64 + rb * 16 + l15;
        ah[rb] = *(const bf16x8*)&Ah[(l4 * 128 + m) * 8];
        al[rb] = *(const bf16x8*)&Al[(l4 * 128 + m) * 8];
      }
      #pragma unroll
      for (int cb = 0; cb < 4; ++cb) {
        const int nn = wn * 64 + cb * 16 + l15;
        bh[cb] = *(const bf16x8*)&Bh[(l4 * 128 + nn) * 8];
        bl[cb] = *(const bf16x8*)&Bl[(l4 * 128 + nn) * 8];
      }
      #pragma unroll
      for (int rb = 0; rb < 4; ++rb)
        #pragma unroll
        for (int cb = 0; cb < 4; ++cb) {
          acc[rb][cb] = __builtin_amdgcn_mfma_f32_16x16x32_bf16(
              ah[rb], bh[cb], acc[rb][cb], 0, 0, 0);
          acc[rb][cb] = __builtin_amdgcn_mfma_f32_16x16x32_bf16(
              ah[rb], bl[cb], acc[rb][cb], 0, 0, 0);
          acc[rb][cb] = __builtin_amdgcn_mfma_f32_16x16x32_bf16(
              al[rb], bh[cb], acc[rb][cb], 0, 0, 0);
        }
      __syncthreads();
    }

    #pragma unroll
    for (int cb = 0; cb < 4; ++cb) {
      const int col = k0 + kt + wn * 64 + cb * 16 + l15;
      const float wv = wsq[col];
      #pragma unroll
      for (int rb = 0; rb < 4; ++rb) {
        f32x4 a = acc[rb][cb];
        #pragma unroll
        for (int rg = 0; rg < 4; ++rg) {
          const float dist = (zzr[rb * 4 + rg] + wv) - 2.0f * a[rg];
          const int s = rb * 4 + rg;
          if (dist < best[s]) { best[s] = dist; bidx[s] = col; }
        }
      }
    }
  }

  #pragma unroll
  for (int rb = 0; rb < 4; ++rb)
    #pragma unroll
    for (int rg = 0; rg < 4; ++rg) {
      const int s = rb * 4 + rg;
      const int R = wm * 64 + rb * 16 + l4 * 4 + rg;
      rv[R * 32 + wn * 16 + l15] = best[s];
      ri[R * 32 + wn * 16 + l15] = bidx[s];
    }
  __syncthreads();

  if (tid < BMT && rt * BMT + tid < n) {
    float bv = INFINITY;
    int bi = 0x7fffffff;
    #pragma unroll
    for (int t = 0; t < 32; ++t) {
      const float v = rv[tid * 32 + t];
      const int ix = ri[tid * 32 + t];
      if (v < bv || (v == bv && ix < bi)) { bv = v; bi = ix; }
    }
    const int row = list[rt * BMT + tid];
    const unsigned long long pk =
        ((unsigned long long)__float_as_uint(bv) << 32) | (unsigned)bi;
    atomicMin(&packed[row], pk);
  }
}

// ---------------------------------------------------------------------------
__global__ __launch_bounds__(256) void final_merge_kernel(
    const int* __restrict__ cnt, const int* __restrict__ list,
    const unsigned long long* __restrict__ packed, int* __restrict__ idx,
    float* __restrict__ out_idx_f, int* __restrict__ hist) {
  const int t = blockIdx.x * 256 + threadIdx.x;
  if (t >= *cnt) return;
  const int row = list[t];
  const int bi = (int)(packed[row] & 0xffffffffULL);
  idx[row] = bi;
  out_idx_f[row] = (float)bi;
  atomicAdd(&hist[bi], 1);
}

// ---------------------------------------------------------------------------
// Gather + straight-through + per-block MSE partial (no global atomics).
// ---------------------------------------------------------------------------
__global__ __launch_bounds__(256) void gather_kernel(
    const float* __restrict__ z, const float* __restrict__ W,
    const int* __restrict__ idx, float* __restrict__ out,
    double* __restrict__ mse_part) {
  __shared__ float wsum[4];
  const int wave = threadIdx.x >> 6;
  const int lane = threadIdx.x & 63;
  const int row = blockIdx.x * 4 + wave;
  const int k = idx[row];
  const float* zr = z + (size_t)row * D_DIM;
  const float* wr = W + (size_t)k * D_DIM;
  float* outr = out + (size_t)row * D_DIM;
  float s = 0.f;
  #pragma unroll
  for (int h = 0; h < 2; ++h) {
    const int c = h * 256 + lane * 4;
    float4 zv = *(const float4*)(zr + c);
    float4 qv = *(const float4*)(wr + c);
    float4 st;
    st.x = zv.x + (qv.x - zv.x);
    st.y = zv.y + (qv.y - zv.y);
    st.z = zv.z + (qv.z - zv.z);
    st.w = zv.w + (qv.w - zv.w);
    float dx = zv.x - qv.x, dy = zv.y - qv.y, dz = zv.z - qv.z, dw = zv.w - qv.w;
    s += dx * dx + dy * dy + dz * dz + dw * dw;
    *(float4*)(outr + c) = st;
  }
  #pragma unroll
  for (int o = 32; o > 0; o >>= 1) s += __shfl_xor(s, o, 64);
  if (lane == 0) wsum[wave] = s;
  __syncthreads();
  if (threadIdx.x == 0)
    mse_part[blockIdx.x] =
        (double)wsum[0] + (double)wsum[1] + (double)wsum[2] + (double)wsum[3];
}

// ---------------------------------------------------------------------------
// Loss: entropy over histogram + MSE partial-sum reduction (8192 partials
// == K_EMB, so both fold into the same strided loop).
// ---------------------------------------------------------------------------
__global__ __launch_bounds__(256) void loss_kernel(
    const int* __restrict__ hist, const double* __restrict__ mse_part,
    float* __restrict__ out_loss) {
  __shared__ float ls[4];
  __shared__ double ld[4];
  const int tid = threadIdx.x;
  float e = 0.f;
  double ms = 0.0;
  for (int b = tid; b < K_EMB; b += 256) {
    float p = (float)hist[b] * (1.0f / 32768.0f);
    e += p * logf(p + 1e-10f);
    ms += mse_part[b];
  }
  #pragma unroll
  for (int o = 32; o > 0; o >>= 1) {
    e += __shfl_xor(e, o, 64);
    ms += __shfl_xor(ms, o, 64);
  }
  if ((tid & 63) == 0) { ls[tid >> 6] = e; ld[tid >> 6] = ms; }
  __syncthreads();
  if (tid == 0) {
    float entropy = -(ls[0] + ls[1] + ls[2] + ls[3]);
    float mse = (float)((ld[0] + ld[1] + ld[2] + ld[3]) / 16777216.0);
    float entropy_loss = 1.0f - entropy / logf(8192.0f);
    out_loss[0] = mse + 0.25f * mse + 0.1f * entropy_loss;
  }
}

// ---------------------------------------------------------------------------
extern "C" void kernel_launch(void* const* d_in, const int* in_sizes, int n_in,
                              void* d_out, int out_size, void* d_ws, size_t ws_size,
                              hipStream_t stream) {
  const float* z = (const float*)d_in[0];  // [32768,512]
  const float* W = (const float*)d_in[1];  // [8192,512]
  float* out = (float*)d_out;              // [B*D] st | [1] loss | [B] indices

  char* ws = (char*)d_ws;
  int*    cnt     = (int*)(ws + 8);                        // @8
  int*    hist    = (int*)(ws + 4096);                     // 32 KB
  unsigned long long* packed = (unsigned long long*)(ws + 65536);  // 256 KB
  float*  zz   = (float*)(ws + 327680);                    // 128 KB
  float*  wsq  = (float*)(ws + 458752);                    // 32 KB
  int*    idx  = (int*)(ws + 491520);                      // 128 KB
  int*    list = (int*)(ws + 622592);                      // 128 KB
  float*  cv1  = (float*)(ws + 786432);                    // [B_ROWS]
  int*    ci1  = (int*)(ws + 1310720);                     // [B_ROWS]
  float*  cv2  = (float*)(ws + 1835008);                   // [B_ROWS]
  double* mse_part = (double*)(ws + 2097152);              // 64 KB [8192]
  float*  cgv1 = (float*)(ws + 2162688);                   // 512 KB [B*4]
  int*    cgi1 = (int*)(ws + 2686976);                     // 512 KB
  float*  cgv2 = (float*)(ws + 3211264);                   // 512 KB (ends 3.7MB)
  short*  zhi  = (short*)(ws + 4194304);                   // 32 MB
  short*  zlo  = (short*)(ws + 37748736);                  // 32 MB
  short*  whi  = (short*)(ws + 71303168);                  // 8 MB
  short*  wlo  = (short*)(ws + 79691776);                  // 8 MB (ends 84 MB)

  hipMemsetAsync(d_ws, 0, 36864, stream);  // cnt + hist

  prep_kernel<<<B_ROWS / 4, 256, 0, stream>>>(z, zhi, zlo, zz, B_ROWS);
  prep_kernel<<<K_EMB / 4, 256, 0, stream>>>(W, whi, wlo, wsq, K_EMB);

  stage1_gemm<<<256 * S1_NG, 256, 0, stream>>>(zhi, whi, wsq, cgv1, cgi1, cgv2);

  merge_groups_kernel<<<B_ROWS / 256, 256, 0, stream>>>(
      cgv1, cgi1, cgv2, cv1, ci1, cv2);

  merge_flag_kernel<<<B_ROWS / 256, 256, 0, stream>>>(
      cv1, ci1, cv2, idx, out + (size_t)B_ROWS * D_DIM + 1, hist,
      packed, cnt, list);

  refine_kernel<<<(B_ROWS / BMT) * RSPLIT, 256, 0, stream>>>(
      zhi, zlo, whi, wlo, zz, wsq, cnt, list, packed);

  final_merge_kernel<<<B_ROWS / 256, 256, 0, stream>>>(
      cnt, list, packed, idx, out + (size_t)B_ROWS * D_DIM + 1, hist);

  gather_kernel<<<B_ROWS / 4, 256, 0, stream>>>(z, W, idx, out, mse_part);

  loss_kernel<<<1, 256, 0, stream>>>(hist, mse_part,
                                     out + (size_t)B_ROWS * D_DIM);
}

// Round 8
// 786.546 us; speedup vs baseline: 3.4975x; 1.7352x over previous
//
#include <hip/hip_runtime.h>
#include <math.h>

#define B_ROWS 32768
#define D_DIM  512
#define K_EMB  8192

#define BMT 128
#define BNT 128
#define RSPLIT 32
#define KRANGE_R (K_EMB / RSPLIT)   // 256
#define EPS 0.10f

typedef __attribute__((ext_vector_type(4))) float f32x4;
typedef __attribute__((ext_vector_type(8))) short bf16x8;

#define GLL16(gp, lp)                                                          \
  __builtin_amdgcn_global_load_lds(                                            \
      (const __attribute__((address_space(1))) void*)(gp),                     \
      (__attribute__((address_space(3))) void*)(lp), 16, 0, 0)

// ---------------------------------------------------------------------------
// fp32 -> bf16 hi + residual lo (RNE), fused with row squared-norm.
// ---------------------------------------------------------------------------
__device__ __forceinline__ unsigned bf_rne(float x) {
  unsigned u = __float_as_uint(x);
  return (u + 0x7fffu + ((u >> 16) & 1u)) >> 16;
}

__global__ __launch_bounds__(256) void prep_kernel(
    const float* __restrict__ X, short* __restrict__ hi,
    short* __restrict__ lo, float* __restrict__ sq, int nrows) {
  const int wave = threadIdx.x >> 6;
  const int lane = threadIdx.x & 63;
  const int row = blockIdx.x * 4 + wave;
  if (row >= nrows) return;
  const float* xr = X + (size_t)row * D_DIM;
  float4 x0 = ((const float4*)xr)[lane * 2];
  float4 x1 = ((const float4*)xr)[lane * 2 + 1];
  float xs[8] = {x0.x, x0.y, x0.z, x0.w, x1.x, x1.y, x1.z, x1.w};
  union { short s[8]; int4 v; } H, L;
  float ssum = 0.f;
  #pragma unroll
  for (int j = 0; j < 8; ++j) {
    unsigned rh = bf_rne(xs[j]);
    H.s[j] = (short)rh;
    float h = __uint_as_float(rh << 16);
    L.s[j] = (short)bf_rne(xs[j] - h);
    ssum += xs[j] * xs[j];
  }
  *(int4*)(hi + (size_t)row * D_DIM + lane * 8) = H.v;
  *(int4*)(lo + (size_t)row * D_DIM + lane * 8) = L.v;
  #pragma unroll
  for (int o = 32; o > 0; o >>= 1) ssum += __shfl_xor(ssum, o, 64);
  if (lane == 0) sq[row] = ssum;
}

// ---------------------------------------------------------------------------
// Stage 1 (V8 = R4-proven design restored + setprio around MFMA cluster).
// R7 post-mortem: the m97 2-barrier GLL16 structure has a ~5100cy per-block
// K-step wall (vmcnt(0) drain tail at 2 blocks/CU) vs this barrier-free
// reg-stream design's ~2515cy; deeper reg pipelines spill (R6: 128-reg cap at
// 4 waves/SIMD). This is the best-known stage1 (536 us). setprio(1) around
// the MFMA cluster applies T5 in its proven regime: free-running waves at
// different phases (no lockstep barriers) -- attn analog measured +4-7%.
// 64-row z-tile persistent in LDS (64 KB) -> 2 blocks/CU, 4 waves/SIMD.
// 512 blocks x 512 threads; wave w owns 64 rows x 32 codes; B streamed
// through registers (depth-1 prefetch). Ascending sweep -> strict `<` argmin
// keeps lowest index on ties.
// ---------------------------------------------------------------------------
__global__ __launch_bounds__(512, 4) void stage1_kernel(
    const short* __restrict__ zhi, const short* __restrict__ whi,
    const float* __restrict__ wsq, float* __restrict__ cv1,
    int* __restrict__ ci1, float* __restrict__ cv2) {
  __shared__ short Zt[32768];   // 64 KB: [dc 0..63][row 0..63][8 bf16]
  float* rv1 = (float*)Zt;             // post-loop overlay: [64][8] f32 (2 KB)
  int*   ri1 = (int*)(Zt + 1024);      // +2 KB
  float* rv2 = (float*)(Zt + 2048);    // +4 KB

  const int tid = threadIdx.x;
  const int lane = tid & 63;
  const int wave = tid >> 6;     // 0..7 = code slice (wn)
  const int l15 = lane & 15, l4 = lane >> 4;
  const int row0 = blockIdx.x * 64;

  // one-time z-tile load (slot = dc*64 + row; LDS dest = slot*16 B)
  #pragma unroll
  for (int j = 0; j < 8; ++j) {
    const int slot = j * 512 + tid;
    const int r = slot & 63, dc = slot >> 6;
    GLL16(zhi + (size_t)(row0 + r) * D_DIM + dc * 8, Zt + (size_t)slot * 8);
  }

  // per-lane B base pointers: code = wave*32 + cb*16 + l15, d-subchunk = l4*8
  const short* pb[2];
  #pragma unroll
  for (int cb = 0; cb < 2; ++cb)
    pb[cb] = whi + (size_t)(wave * 32 + cb * 16 + l15) * D_DIM + l4 * 8;

  float v1[16], v2[16];
  int   i1[16];
  #pragma unroll
  for (int s = 0; s < 16; ++s) { v1[s] = INFINITY; v2[s] = INFINITY; i1[s] = 0x7fffffff; }

  // prefetch first B chunk into registers (independent of LDS)
  bf16x8 bcur[2];
  #pragma unroll
  for (int cb = 0; cb < 2; ++cb) bcur[cb] = *(const bf16x8*)(pb[cb]);

  __syncthreads();  // z-tile DMA complete & visible; the ONLY pre-loop barrier

  for (int kt = 0; kt < K_EMB; kt += 256) {
    f32x4 acc[4][2];
    #pragma unroll
    for (int rb = 0; rb < 4; ++rb)
      #pragma unroll
      for (int cb = 0; cb < 2; ++cb) acc[rb][cb] = (f32x4)0.f;

    #pragma unroll 4
    for (int dc = 0; dc < 16; ++dc) {
      // issue next-chunk B loads (next d-chunk, or chunk 0 of next k-tile)
      const int nt0 = (dc == 15) ? kt + 256 : kt;
      const int nt = (nt0 < K_EMB) ? nt0 : 0;      // tail: harmless dummy load
      const int nd = (dc == 15) ? 0 : (dc + 1) * 32;
      const size_t noff = (size_t)nt * D_DIM + nd;
      bf16x8 bnxt[2];
      #pragma unroll
      for (int cb = 0; cb < 2; ++cb) bnxt[cb] = *(const bf16x8*)(pb[cb] + noff);

      bf16x8 a[4];
      #pragma unroll
      for (int rb = 0; rb < 4; ++rb)
        a[rb] = *(const bf16x8*)&Zt[((dc * 4 + l4) * 64 + rb * 16 + l15) * 8];
      __builtin_amdgcn_s_setprio(1);
      #pragma unroll
      for (int rb = 0; rb < 4; ++rb)
        #pragma unroll
        for (int cb = 0; cb < 2; ++cb)
          acc[rb][cb] = __builtin_amdgcn_mfma_f32_16x16x32_bf16(
              a[rb], bcur[cb], acc[rb][cb], 0, 0, 0);
      __builtin_amdgcn_s_setprio(0);
      #pragma unroll
      for (int cb = 0; cb < 2; ++cb) bcur[cb] = bnxt[cb];
    }

    // score 256-code tile; C/D layout: col=lane&15, row=(lane>>4)*4+reg.
    // ascending sweep -> strict `<` keeps the lowest index on ties.
    #pragma unroll
    for (int cb = 0; cb < 2; ++cb) {
      const int col = kt + wave * 32 + cb * 16 + l15;
      const float wv = wsq[col];
      #pragma unroll
      for (int rb = 0; rb < 4; ++rb) {
        f32x4 a = acc[rb][cb];
        #pragma unroll
        for (int rg = 0; rg < 4; ++rg) {
          const float dist = wv - 2.0f * a[rg];
          const int s = rb * 4 + rg;
          if (dist < v1[s]) {
            v2[s] = v1[s]; v1[s] = dist; i1[s] = col;
          } else {
            v2[s] = fminf(v2[s], dist);
          }
        }
      }
    }
  }

  // in-register top-2 merge across the 16 col-classes (lanes l4*16 .. +15
  // all hold the same physical rows; xor masks 1,2,4,8 stay in-group).
  __syncthreads();  // compute done; Zt dead -> overlay
  #pragma unroll
  for (int s = 0; s < 16; ++s) {
    float a1 = v1[s], a2 = v2[s];
    int ai = i1[s];
    #pragma unroll
    for (int m = 1; m < 16; m <<= 1) {
      const float b1 = __shfl_xor(a1, m, 64);
      const float b2 = __shfl_xor(a2, m, 64);
      const int   bi = __shfl_xor(ai, m, 64);
      if (b1 < a1 || (b1 == a1 && bi < ai)) {
        a2 = fminf(a1, b2); a1 = b1; ai = bi;
      } else {
        a2 = fminf(a2, b1);
      }
    }
    if (l15 == 0) {
      const int r = (s >> 2) * 16 + l4 * 4 + (s & 3);
      rv1[r * 8 + wave] = a1;
      ri1[r * 8 + wave] = ai;
      rv2[r * 8 + wave] = a2;
    }
  }
  __syncthreads();

  if (tid < 64) {
    float V1 = INFINITY, V2 = INFINITY;
    int I1 = 0x7fffffff;
    #pragma unroll
    for (int w = 0; w < 8; ++w) {
      const float a1 = rv1[tid * 8 + w];
      const int ai = ri1[tid * 8 + w];
      const float a2 = rv2[tid * 8 + w];
      if (a1 < V1 || (a1 == V1 && ai < I1)) {
        V2 = fminf(V1, a2); V1 = a1; I1 = ai;
      } else {
        V2 = fminf(V2, a1);
      }
    }
    cv1[row0 + tid] = V1; ci1[row0 + tid] = I1; cv2[row0 + tid] = V2;
  }
}

// ---------------------------------------------------------------------------
// Commit unambiguous rows; compact ambiguous rows into refine list.
// ---------------------------------------------------------------------------
__global__ __launch_bounds__(256) void merge_flag_kernel(
    const float* __restrict__ cv1, const int* __restrict__ ci1,
    const float* __restrict__ cv2, int* __restrict__ idx,
    float* __restrict__ out_idx_f, int* __restrict__ hist,
    unsigned long long* __restrict__ packed, int* __restrict__ cnt,
    int* __restrict__ list) {
  const int row = blockIdx.x * 256 + threadIdx.x;
  const float V1 = cv1[row];
  const int I1 = ci1[row];
  const float V2 = cv2[row];
  if (V2 - V1 >= EPS) {
    idx[row] = I1;
    out_idx_f[row] = (float)I1;
    atomicAdd(&hist[I1], 1);
  } else {
    packed[row] = 0xffffffffffffffffULL;
    const int p = atomicAdd(cnt, 1);
    list[p] = row;
  }
}

// ---------------------------------------------------------------------------
// Refine: exact 3-pass distance argmin over ALL codes for flagged rows.
// V8: RSPLIT 16 -> 32. With n ambiguous rows ~2K, RSPLIT=16 left only ~256
// working blocks (1/CU), each serializing 64 K-steps of the 2-barrier wall.
// Halving the K-range per block doubles co-resident working blocks (2/CU)
// -> refine time ~halves. Packed atomicMin merge is split-count-agnostic.
// ---------------------------------------------------------------------------
__global__ __launch_bounds__(256, 2) void refine_kernel(
    const short* __restrict__ zhi, const short* __restrict__ zlo,
    const short* __restrict__ whi, const short* __restrict__ wlo,
    const float* __restrict__ zz, const float* __restrict__ wsq,
    const int* __restrict__ cnt, const int* __restrict__ list,
    unsigned long long* __restrict__ packed) {
  __shared__ char smem[32768];
  short* Ah = (short*)smem;
  short* Al = (short*)(smem + 8192);
  short* Bh = (short*)(smem + 16384);
  short* Bl = (short*)(smem + 24576);
  float* rv = (float*)smem;
  int*   ri = (int*)(smem + 16384);

  const int n = *cnt;
  const int bx = blockIdx.x;
  const int rt = bx >> 5;
  const int ks = bx & 31;
  if (rt * BMT >= n) return;
  const int k0 = ks * KRANGE_R;

  const int tid = threadIdx.x;
  const int lane = tid & 63;
  const int wave = tid >> 6;
  const int wm = wave >> 1, wn = wave & 1;
  const int l15 = lane & 15, l4 = lane >> 4;

  const int r0s = tid & 127;
  const int kc0 = tid >> 7;
  const int kc1 = kc0 + 2;
  const int rowg = list[min(rt * BMT + r0s, n - 1)];

  float zzr[16];
  #pragma unroll
  for (int rb = 0; rb < 4; ++rb)
    #pragma unroll
    for (int rg = 0; rg < 4; ++rg) {
      const int m = wm * 64 + rb * 16 + l4 * 4 + rg;
      zzr[rb * 4 + rg] = zz[list[min(rt * BMT + m, n - 1)]];
    }

  float best[16];
  int   bidx[16];
  #pragma unroll
  for (int s = 0; s < 16; ++s) { best[s] = INFINITY; bidx[s] = 0x7fffffff; }

  for (int kt = 0; kt < KRANGE_R; kt += BNT) {
    f32x4 acc[4][4];
    #pragma unroll
    for (int rb = 0; rb < 4; ++rb)
      #pragma unroll
      for (int cb = 0; cb < 4; ++cb) acc[rb][cb] = (f32x4)0.f;

    for (int d0 = 0; d0 < D_DIM; d0 += 32) {
      const size_t ga0 = (size_t)rowg * D_DIM + d0 + kc0 * 8;
      const size_t ga1 = (size_t)rowg * D_DIM + d0 + kc1 * 8;
      const size_t gb0 = (size_t)(k0 + kt + r0s) * D_DIM + d0 + kc0 * 8;
      const size_t gb1 = (size_t)(k0 + kt + r0s) * D_DIM + d0 + kc1 * 8;
      GLL16(zhi + ga0, Ah + (size_t)tid * 8);
      GLL16(zhi + ga1, Ah + (size_t)(tid + 256) * 8);
      GLL16(zlo + ga0, Al + (size_t)tid * 8);
      GLL16(zlo + ga1, Al + (size_t)(tid + 256) * 8);
      GLL16(whi + gb0, Bh + (size_t)tid * 8);
      GLL16(whi + gb1, Bh + (size_t)(tid + 256) * 8);
      GLL16(wlo + gb0, Bl + (size_t)tid * 8);
      GLL16(wlo + gb1, Bl + (size_t)(tid + 256) * 8);
      __syncthreads();

      bf16x8 ah[4], al[4], bh[4], bl[4];
      #pragma unroll
      for (int rb = 0; rb < 4; ++rb) {
        const int m = wm * 64 + rb * 16 + l15;
        ah[rb] = *(const bf16x8*)&Ah[(l4 * 128 + m) * 8];
        al[rb] = *(const bf16x8*)&Al[(l4 * 128 + m) * 8];
      }
      #pragma unroll
      for (int cb = 0; cb < 4; ++cb) {
        const int nn = wn * 64 + cb * 16 + l15;
        bh[cb] = *(const bf16x8*)&Bh[(l4 * 128 + nn) * 8];
        bl[cb] = *(const bf16x8*)&Bl[(l4 * 128 + nn) * 8];
      }
      #pragma unroll
      for (int rb = 0; rb < 4; ++rb)
        #pragma unroll
        for (int cb = 0; cb < 4; ++cb) {
          acc[rb][cb] = __builtin_amdgcn_mfma_f32_16x16x32_bf16(
              ah[rb], bh[cb], acc[rb][cb], 0, 0, 0);
          acc[rb][cb] = __builtin_amdgcn_mfma_f32_16x16x32_bf16(
              ah[rb], bl[cb], acc[rb][cb], 0, 0, 0);
          acc[rb][cb] = __builtin_amdgcn_mfma_f32_16x16x32_bf16(
              al[rb], bh[cb], acc[rb][cb], 0, 0, 0);
        }
      __syncthreads();
    }

    #pragma unroll
    for (int cb = 0; cb < 4; ++cb) {
      const int col = k0 + kt + wn * 64 + cb * 16 + l15;
      const float wv = wsq[col];
      #pragma unroll
      for (int rb = 0; rb < 4; ++rb) {
        f32x4 a = acc[rb][cb];
        #pragma unroll
        for (int rg = 0; rg < 4; ++rg) {
          const float dist = (zzr[rb * 4 + rg] + wv) - 2.0f * a[rg];
          const int s = rb * 4 + rg;
          if (dist < best[s]) { best[s] = dist; bidx[s] = col; }
        }
      }
    }
  }

  #pragma unroll
  for (int rb = 0; rb < 4; ++rb)
    #pragma unroll
    for (int rg = 0; rg < 4; ++rg) {
      const int s = rb * 4 + rg;
      const int R = wm * 64 + rb * 16 + l4 * 4 + rg;
      rv[R * 32 + wn * 16 + l15] = best[s];
      ri[R * 32 + wn * 16 + l15] = bidx[s];
    }
  __syncthreads();

  if (tid < BMT && rt * BMT + tid < n) {
    float bv = INFINITY;
    int bi = 0x7fffffff;
    #pragma unroll
    for (int t = 0; t < 32; ++t) {
      const float v = rv[tid * 32 + t];
      const int ix = ri[tid * 32 + t];
      if (v < bv || (v == bv && ix < bi)) { bv = v; bi = ix; }
    }
    const int row = list[rt * BMT + tid];
    const unsigned long long pk =
        ((unsigned long long)__float_as_uint(bv) << 32) | (unsigned)bi;
    atomicMin(&packed[row], pk);
  }
}

// ---------------------------------------------------------------------------
__global__ __launch_bounds__(256) void final_merge_kernel(
    const int* __restrict__ cnt, const int* __restrict__ list,
    const unsigned long long* __restrict__ packed, int* __restrict__ idx,
    float* __restrict__ out_idx_f, int* __restrict__ hist) {
  const int t = blockIdx.x * 256 + threadIdx.x;
  if (t >= *cnt) return;
  const int row = list[t];
  const int bi = (int)(packed[row] & 0xffffffffULL);
  idx[row] = bi;
  out_idx_f[row] = (float)bi;
  atomicAdd(&hist[bi], 1);
}

// ---------------------------------------------------------------------------
// Gather + straight-through + per-block MSE partial (no global atomics).
// ---------------------------------------------------------------------------
__global__ __launch_bounds__(256) void gather_kernel(
    const float* __restrict__ z, const float* __restrict__ W,
    const int* __restrict__ idx, float* __restrict__ out,
    double* __restrict__ mse_part) {
  __shared__ float wsum[4];
  const int wave = threadIdx.x >> 6;
  const int lane = threadIdx.x & 63;
  const int row = blockIdx.x * 4 + wave;
  const int k = idx[row];
  const float* zr = z + (size_t)row * D_DIM;
  const float* wr = W + (size_t)k * D_DIM;
  float* outr = out + (size_t)row * D_DIM;
  float s = 0.f;
  #pragma unroll
  for (int h = 0; h < 2; ++h) {
    const int c = h * 256 + lane * 4;
    float4 zv = *(const float4*)(zr + c);
    float4 qv = *(const float4*)(wr + c);
    float4 st;
    st.x = zv.x + (qv.x - zv.x);
    st.y = zv.y + (qv.y - zv.y);
    st.z = zv.z + (qv.z - zv.z);
    st.w = zv.w + (qv.w - zv.w);
    float dx = zv.x - qv.x, dy = zv.y - qv.y, dz = zv.z - qv.z, dw = zv.w - qv.w;
    s += dx * dx + dy * dy + dz * dz + dw * dw;
    *(float4*)(outr + c) = st;
  }
  #pragma unroll
  for (int o = 32; o > 0; o >>= 1) s += __shfl_xor(s, o, 64);
  if (lane == 0) wsum[wave] = s;
  __syncthreads();
  if (threadIdx.x == 0)
    mse_part[blockIdx.x] =
        (double)wsum[0] + (double)wsum[1] + (double)wsum[2] + (double)wsum[3];
}

// ---------------------------------------------------------------------------
// Loss: entropy over histogram + MSE partial-sum reduction (8192 partials
// == K_EMB, so both fold into the same strided loop).
// ---------------------------------------------------------------------------
__global__ __launch_bounds__(256) void loss_kernel(
    const int* __restrict__ hist, const double* __restrict__ mse_part,
    float* __restrict__ out_loss) {
  __shared__ float ls[4];
  __shared__ double ld[4];
  const int tid = threadIdx.x;
  float e = 0.f;
  double ms = 0.0;
  for (int b = tid; b < K_EMB; b += 256) {
    float p = (float)hist[b] * (1.0f / 32768.0f);
    e += p * logf(p + 1e-10f);
    ms += mse_part[b];
  }
  #pragma unroll
  for (int o = 32; o > 0; o >>= 1) {
    e += __shfl_xor(e, o, 64);
    ms += __shfl_xor(ms, o, 64);
  }
  if ((tid & 63) == 0) { ls[tid >> 6] = e; ld[tid >> 6] = ms; }
  __syncthreads();
  if (tid == 0) {
    float entropy = -(ls[0] + ls[1] + ls[2] + ls[3]);
    float mse = (float)((ld[0] + ld[1] + ld[2] + ld[3]) / 16777216.0);
    float entropy_loss = 1.0f - entropy / logf(8192.0f);
    out_loss[0] = mse + 0.25f * mse + 0.1f * entropy_loss;
  }
}

// ---------------------------------------------------------------------------
extern "C" void kernel_launch(void* const* d_in, const int* in_sizes, int n_in,
                              void* d_out, int out_size, void* d_ws, size_t ws_size,
                              hipStream_t stream) {
  const float* z = (const float*)d_in[0];  // [32768,512]
  const float* W = (const float*)d_in[1];  // [8192,512]
  float* out = (float*)d_out;              // [B*D] st | [1] loss | [B] indices

  char* ws = (char*)d_ws;
  int*    cnt     = (int*)(ws + 8);                        // @8
  int*    hist    = (int*)(ws + 4096);                     // 32 KB
  unsigned long long* packed = (unsigned long long*)(ws + 65536);  // 256 KB
  float*  zz   = (float*)(ws + 327680);                    // 128 KB
  float*  wsq  = (float*)(ws + 458752);                    // 32 KB
  int*    idx  = (int*)(ws + 491520);                      // 128 KB
  int*    list = (int*)(ws + 622592);                      // 128 KB
  float*  cv1  = (float*)(ws + 786432);                    // [B_ROWS]
  int*    ci1  = (int*)(ws + 1310720);                     // [B_ROWS]
  float*  cv2  = (float*)(ws + 1835008);                   // [B_ROWS]
  double* mse_part = (double*)(ws + 2097152);              // 64 KB [8192]
  short*  zhi  = (short*)(ws + 4194304);                   // 32 MB
  short*  zlo  = (short*)(ws + 37748736);                  // 32 MB
  short*  whi  = (short*)(ws + 71303168);                  // 8 MB
  short*  wlo  = (short*)(ws + 79691776);                  // 8 MB (ends 84 MB)

  hipMemsetAsync(d_ws, 0, 36864, stream);  // cnt + hist

  prep_kernel<<<B_ROWS / 4, 256, 0, stream>>>(z, zhi, zlo, zz, B_ROWS);
  prep_kernel<<<K_EMB / 4, 256, 0, stream>>>(W, whi, wlo, wsq, K_EMB);

  stage1_kernel<<<B_ROWS / 64, 512, 0, stream>>>(zhi, whi, wsq, cv1, ci1, cv2);

  merge_flag_kernel<<<B_ROWS / 256, 256, 0, stream>>>(
      cv1, ci1, cv2, idx, out + (size_t)B_ROWS * D_DIM + 1, hist,
      packed, cnt, list);

  refine_kernel<<<(B_ROWS / BMT) * RSPLIT, 256, 0, stream>>>(
      zhi, zlo, whi, wlo, zz, wsq, cnt, list, packed);

  final_merge_kernel<<<B_ROWS / 256, 256, 0, stream>>>(
      cnt, list, packed, idx, out + (size_t)B_ROWS * D_DIM + 1, hist);

  gather_kernel<<<B_ROWS / 4, 256, 0, stream>>>(z, W, idx, out, mse_part);

  loss_kernel<<<1, 256, 0, stream>>>(hist, mse_part,
                                     out + (size_t)B_ROWS * D_DIM);
}